// Round 6
// baseline (1176.732 us; speedup 1.0000x reference)
//
#include <hip/hip_runtime.h>
#include <hip/hip_bf16.h>
#include <math.h>

typedef float f32x4 __attribute__((ext_vector_type(4)));
using bf16x8 = __attribute__((ext_vector_type(8))) short;
using f32x16 = __attribute__((ext_vector_type(16))) float;
typedef unsigned short ushortT;
using u16x4 = __attribute__((ext_vector_type(4))) unsigned short;

__device__ __forceinline__ ushortT f2bf(float f) {
  unsigned int u = __builtin_bit_cast(unsigned int, f);
  u = (u + 0x7FFFu + ((u >> 16) & 1u)) >> 16;
  return (ushortT)u;
}
__device__ __forceinline__ float bf2f(ushortT u) {
  return __builtin_bit_cast(float, (unsigned int)u << 16);
}
__device__ __forceinline__ void gload_lds16(const void* gsrc, void* ldst) {
  __builtin_amdgcn_global_load_lds(
      (const __attribute__((address_space(1))) unsigned int*)gsrc,
      (__attribute__((address_space(3))) unsigned int*)ldst, 16, 0, 0);
}

// emb tiled layout: emb_t[(row>>5)*32768 + kc*256 + (row&31)*8 + j], k=kc*8+j

// ---------------------------------------------------------------------------
// Prepack: bf16 MFMA fragment layouts + u = cls_W @ out_W + cbdot scalar.
// ---------------------------------------------------------------------------
__global__ __launch_bounds__(256) void prepack_kernel(
    const float* __restrict__ w1, const float* __restrict__ w2,
    const float* __restrict__ aW1, const float* __restrict__ aW2,
    const float* __restrict__ aW3, const float* __restrict__ cls_W,
    const float* __restrict__ cls_b, const float* __restrict__ out_W,
    const float* __restrict__ out_b, ushortT* __restrict__ Bp1,
    ushortT* __restrict__ Bp2, ushortT* __restrict__ BpA1,
    ushortT* __restrict__ BpA2, ushortT* __restrict__ BpA3,
    float* __restrict__ u) {
  const int i = blockIdx.x * 256 + threadIdx.x;
  const int n1 = 1024, n2 = 51200, nA = 262144, nU = 65536;
  if (i < n1) {
    int nt = i >> 9, l = (i >> 3) & 63, j = i & 7;
    int tap = ((l >> 4) << 3) + j, ch = nt * 16 + (l & 15);
    Bp1[i] = (tap < 25) ? f2bf(w1[tap * 32 + ch]) : (ushortT)0;
  } else if (i < n1 + n2) {
    int t = i - n1;
    int co = t & 63, k = t >> 6;  // coalesced read over co
    int s = k >> 4, hi = (k >> 3) & 1, j = k & 7;
    int nt = co >> 5, l31 = co & 31;
    Bp2[(s * 2 + nt) * 512 + (hi * 32 + l31) * 8 + j] = f2bf(w2[k * 64 + co]);
  } else if (i < n1 + n2 + 3 * nA) {
    int t = i - n1 - n2;
    int m = t >> 18, r = t & (nA - 1);
    const float* aW = (m == 0) ? aW1 : ((m == 1) ? aW2 : aW3);
    ushortT* dst = (m == 0) ? BpA1 : ((m == 1) ? BpA2 : BpA3);
    int col = r & 255, k = r >> 8;  // coalesced read over col
    int nt = col >> 5, l31 = col & 31;
    int s = k >> 4, hi = (k >> 3) & 1, j = k & 7;
    dst[nt * 32768 + s * 512 + (hi * 32 + l31) * 8 + j] =
        f2bf(aW[k * 256 + col]);
  } else if (i < n1 + n2 + 3 * nA + nU) {
    int t = i - (n1 + n2 + 3 * nA);
    int k = t >> 6, lane = t & 63;
    float p = 0.f;
#pragma unroll
    for (int j = 0; j < 8; ++j) {
      int jj = lane + j * 64;
      p += cls_W[k * 512 + jj] * out_W[jj];
    }
#pragma unroll
    for (int off = 32; off; off >>= 1) p += __shfl_xor(p, off, 64);
    if (lane == 0) u[k] = p;
  } else if (i < n1 + n2 + 3 * nA + nU + 64) {
    int lane = i - (n1 + n2 + 3 * nA + nU);
    float p = 0.f;
#pragma unroll
    for (int j = 0; j < 8; ++j) {
      int jj = lane * 8 + j;
      p += cls_b[jj] * out_W[jj];
    }
#pragma unroll
    for (int off = 32; off; off >>= 1) p += __shfl_xor(p, off, 64);
    if (lane == 0) u[1024] = p + out_b[0];
  }
}

// ---------------------------------------------------------------------------
// Fused conv: 4 instances/block, one wave per instance. conv2 B double-
// buffered in LDS (4 K-steps per chunk). h1 stride 36 (16 bank-starts).
// ---------------------------------------------------------------------------
#define PADW 36
__global__ __launch_bounds__(256, 2) void fused_conv_mfma_kernel(
    const float* __restrict__ x, const ushortT* __restrict__ Bp1,
    const float* __restrict__ b1g, const ushortT* __restrict__ Bp2,
    const float* __restrict__ b2g, ushortT* __restrict__ emb1) {
  __shared__ ushortT h1s[4][144 * PADW];        // 41472 B
  __shared__ __align__(16) char uni[4 * 2080];  // xs / epi slabs
  __shared__ ushortT Bbuf[2][4096];             // 2 x 8KB chunks (4 K-steps)

  const int tid = threadIdx.x, wv = tid >> 6, lane = tid & 63;
  const int inst = blockIdx.x * 4 + wv;
  ushortT* xs = (ushortT*)(uni + wv * 2080);
  ushortT* h1w = &h1s[wv][0];

  // stage conv2 B chunk 0 (overlaps conv1)
  {
    int base = wv * 2048;
    gload_lds16((const char*)Bp2 + base + lane * 16, (char*)&Bbuf[0][0] + base);
    gload_lds16((const char*)Bp2 + base + 1024 + lane * 16,
                (char*)&Bbuf[0][0] + base + 1024);
  }

  // x -> bf16 LDS (wave-private)
  {
    const float* xg = x + (size_t)inst * 784;
#pragma unroll
    for (int t = 0; t < 4; ++t) {
      int g = lane + t * 64;
      if (g < 196) {
        f32x4 v = *(const f32x4*)&xg[g * 4];
        u16x4 o;
#pragma unroll
        for (int z = 0; z < 4; ++z) o[z] = f2bf(v[z]);
        *(u16x4*)&xs[g * 4] = o;
      }
    }
  }

  // ---------------- conv1 via MFMA 16x16x32 (wave-private) ----------------
  {
    const int arow = lane & 15, kg = lane >> 4;
    int koff[8], kval[8];
#pragma unroll
    for (int j = 0; j < 8; ++j) {
      int tap = kg * 8 + j;
      int ky = (tap * 13) >> 6;
      int kx = tap - ky * 5;
      kval[j] = (tap < 25);
      koff[j] = kval[j] ? (ky * 28 + kx) : 0;
    }
    bf16x8 w1f0 = *(const bf16x8*)&Bp1[lane * 8];
    bf16x8 w1f1 = *(const bf16x8*)&Bp1[(64 + lane) * 8];
    const float bA = b1g[arow], bB = b1g[16 + arow];

#pragma unroll 4
    for (int g = 0; g < 36; ++g) {
      int R = g * 16 + arow;
      int q = R >> 2, quad = R & 3;
      int qy = q / 12, qx = q - qy * 12;
      int base = (2 * qy + (quad >> 1)) * 28 + 2 * qx + (quad & 1);
      bf16x8 a;
#pragma unroll
      for (int j = 0; j < 8; ++j) {
        ushortT vv = xs[base + koff[j]];
        a[j] = (short)(kval[j] ? vv : (ushortT)0);
      }
      f32x4 c0, c1;
#pragma unroll
      for (int z = 0; z < 4; ++z) { c0[z] = 0.f; c1[z] = 0.f; }
      c0 = __builtin_amdgcn_mfma_f32_16x16x32_bf16(a, w1f0, c0, 0, 0, 0);
      c1 = __builtin_amdgcn_mfma_f32_16x16x32_bf16(a, w1f1, c1, 0, 0, 0);
      int qo = g * 4 + kg;
      float m0 = fmaxf(fmaxf(c0[0], c0[1]), fmaxf(c0[2], c0[3]));
      float m1 = fmaxf(fmaxf(c1[0], c1[1]), fmaxf(c1[2], c1[3]));
      h1w[qo * PADW + arow] = f2bf(fmaxf(m0 + bA, 0.f));
      h1w[qo * PADW + 16 + arow] = f2bf(fmaxf(m1 + bB, 0.f));
    }
  }
  __syncthreads();  // h1 done; chunk 0 landed (barrier drains vmcnt)

  // ---------------- conv2 via MFMA 32x32x16 (LDS dbuf B) ------------------
  {
    const int hi = lane >> 5, l31 = lane & 31;
    int rowbase0, rowbase1;
    {
      int q2 = l31 >> 2, quad2 = l31 & 3;
      rowbase0 = (2 * (q2 >> 2) + (quad2 >> 1)) * 12 + 2 * (q2 & 3) + (quad2 & 1);
      q2 = (32 + l31) >> 2;
      rowbase1 = (2 * (q2 >> 2) + (quad2 >> 1)) * 12 + 2 * (q2 & 3) + (quad2 & 1);
    }
    const int ab0 = rowbase0 * PADW + hi * 8;
    const int ab1 = rowbase1 * PADW + hi * 8;

    f32x16 a00, a01, a10, a11;
#pragma unroll
    for (int z = 0; z < 16; ++z) { a00[z] = 0.f; a01[z] = 0.f; a10[z] = 0.f; a11[z] = 0.f; }

    for (int c = 0; c < 13; ++c) {
      if (c < 12) {  // stage chunk c+1
        char* dstb = (char*)&Bbuf[(c + 1) & 1][0];
        const char* srcb = (const char*)Bp2 + (size_t)(c + 1) * 8192;
        if (c + 1 < 12) {
          gload_lds16(srcb + wv * 2048 + lane * 16, dstb + wv * 2048);
          gload_lds16(srcb + wv * 2048 + 1024 + lane * 16,
                      dstb + wv * 2048 + 1024);
        } else {
          gload_lds16(srcb + wv * 1024 + lane * 16, dstb + wv * 1024);
        }
      }
      const ushortT* bb = &Bbuf[c & 1][0];
      const int ns = (c < 12) ? 4 : 2;
#pragma unroll
      for (int i = 0; i < 4; ++i) {
        if (i < ns) {
          int s = c * 4 + i;
          int tap = s >> 1;
          int ky = (tap * 13) >> 6, kx = tap - ky * 5;
          int aoff = (ky * 12 + kx) * PADW + ((s & 1) << 4);
          bf16x8 bf0 = *(const bf16x8*)&bb[i * 1024 + lane * 8];
          bf16x8 bf1 = *(const bf16x8*)&bb[i * 1024 + 512 + lane * 8];
          bf16x8 af0 = *(const bf16x8*)&h1w[ab0 + aoff];
          bf16x8 af1 = *(const bf16x8*)&h1w[ab1 + aoff];
          a00 = __builtin_amdgcn_mfma_f32_32x32x16_bf16(af0, bf0, a00, 0, 0, 0);
          a01 = __builtin_amdgcn_mfma_f32_32x32x16_bf16(af0, bf1, a01, 0, 0, 0);
          a10 = __builtin_amdgcn_mfma_f32_32x32x16_bf16(af1, bf0, a10, 0, 0, 0);
          a11 = __builtin_amdgcn_mfma_f32_32x32x16_bf16(af1, bf1, a11, 0, 0, 0);
        }
      }
      __syncthreads();
    }

    // epilogue: bias + pool + relu -> wave-private epi slab (flat k = p*64+c)
    ushortT* epi = (ushortT*)(uni + wv * 2080);
    const float b2_0 = b2g[l31], b2_1 = b2g[32 + l31];
#pragma unroll
    for (int rg = 0; rg < 4; ++rg) {
      float m00 = fmaxf(fmaxf(a00[rg * 4], a00[rg * 4 + 1]),
                        fmaxf(a00[rg * 4 + 2], a00[rg * 4 + 3]));
      float m01 = fmaxf(fmaxf(a01[rg * 4], a01[rg * 4 + 1]),
                        fmaxf(a01[rg * 4 + 2], a01[rg * 4 + 3]));
      float m10 = fmaxf(fmaxf(a10[rg * 4], a10[rg * 4 + 1]),
                        fmaxf(a10[rg * 4 + 2], a10[rg * 4 + 3]));
      float m11 = fmaxf(fmaxf(a11[rg * 4], a11[rg * 4 + 1]),
                        fmaxf(a11[rg * 4 + 2], a11[rg * 4 + 3]));
      int p0 = 2 * rg + hi, p1 = 8 + 2 * rg + hi;
      epi[p0 * 64 + l31] = f2bf(fmaxf(m00 + b2_0, 0.f));
      epi[p0 * 64 + 32 + l31] = f2bf(fmaxf(m01 + b2_1, 0.f));
      epi[p1 * 64 + l31] = f2bf(fmaxf(m10 + b2_0, 0.f));
      epi[p1 * 64 + 32 + l31] = f2bf(fmaxf(m11 + b2_1, 0.f));
    }
  }
  __syncthreads();

  // cooperative tiled store
  {
    const int bid = blockIdx.x;
    ushortT* dstbase = emb1 + (size_t)(bid >> 3) * 32768;
    const int instoff = 4 * (bid & 7);
#pragma unroll
    for (int z = 0; z < 2; ++z) {
      int kchunk = (tid >> 2) + z * 64;
      int i = tid & 3;
      bf16x8 vv = *(const bf16x8*)(uni + i * 2080 + kchunk * 16);
      *(bf16x8*)&dstbase[(size_t)kchunk * 256 + (instoff + i) * 8] = vv;
    }
  }
}

// ---------------------------------------------------------------------------
// Persistent fused tail: att1 -> softmax1 -> segsum1 -> att2 -> softmax2 ->
// segsum2 -> att3 -> softmax3 -> head. 512 blocks x 256 (2/CU, co-resident).
// ---------------------------------------------------------------------------
__device__ __forceinline__ void gsync(unsigned* cnt, unsigned nb) {
  __threadfence();
  __syncthreads();
  if (threadIdx.x == 0) {
    atomicAdd(cnt, 1u);
    while (atomicAdd(cnt, 0u) < nb) __builtin_amdgcn_s_sleep(8);
  }
  __syncthreads();
  __threadfence();
}

// 32-row attention-score tile: s_out[r] = sigmoid(tanh(row@W+b)@v+vb)
__device__ void att32(const ushortT* __restrict__ atile,
                      const ushortT* __restrict__ Bp,
                      const float* __restrict__ bias,
                      const float* __restrict__ v, float vb0,
                      float* __restrict__ s_out) {
  __shared__ float part[32][4];
  const int tid = threadIdx.x, wv = tid >> 6, lane = tid & 63;
  const int hi = lane >> 5, l31 = lane & 31;
  const ushortT* ap = atile + hi * 256 + l31 * 8;
  const ushortT* bp0 = Bp + (size_t)(2 * wv) * 32768 + (size_t)lane * 8;
  const ushortT* bp1 = bp0 + 32768;

  f32x16 a0, a1;
#pragma unroll
  for (int z = 0; z < 16; ++z) { a0[z] = 0.f; a1[z] = 0.f; }

#pragma unroll 8
  for (int s = 0; s < 64; ++s) {
    bf16x8 af = *(const bf16x8*)(ap + s * 512);
    bf16x8 b0 = *(const bf16x8*)(bp0 + s * 512);
    bf16x8 b1 = *(const bf16x8*)(bp1 + s * 512);
    a0 = __builtin_amdgcn_mfma_f32_32x32x16_bf16(af, b0, a0, 0, 0, 0);
    a1 = __builtin_amdgcn_mfma_f32_32x32x16_bf16(af, b1, a1, 0, 0, 0);
  }

  const int c0 = wv * 64 + l31, c1 = c0 + 32;
  const float bc0 = bias[c0], vc0 = v[c0];
  const float bc1 = bias[c1], vc1 = v[c1];
#pragma unroll
  for (int r = 0; r < 16; ++r) {
    float p = tanhf(a0[r] + bc0) * vc0 + tanhf(a1[r] + bc1) * vc1;
#pragma unroll
    for (int off = 16; off >= 1; off >>= 1) p += __shfl_xor(p, off, 64);
    if (l31 == 0) part[(r & 3) + 8 * (r >> 2) + 4 * hi][wv] = p;
  }
  __syncthreads();
  if (tid < 32) {
    float ss = vb0 + part[tid][0] + part[tid][1] + part[tid][2] + part[tid][3];
    s_out[tid] = 1.f / (1.f + expf(-ss));
  }
  __syncthreads();
}

__device__ void smr_block(const float* __restrict__ s, int M,
                          float* __restrict__ red) {
  __shared__ float sm[4], ssm[4];
  const int tid = threadIdx.x;
  float mx = -1e30f;
  for (int i = tid; i < M; i += 256) mx = fmaxf(mx, s[i]);
#pragma unroll
  for (int off = 32; off; off >>= 1) mx = fmaxf(mx, __shfl_xor(mx, off, 64));
  if ((tid & 63) == 0) sm[tid >> 6] = mx;
  __syncthreads();
  float g = fmaxf(fmaxf(sm[0], sm[1]), fmaxf(sm[2], sm[3]));
  float su = 0.f;
  for (int i = tid; i < M; i += 256) su += expf(s[i] - g);
#pragma unroll
  for (int off = 32; off; off >>= 1) su += __shfl_xor(su, off, 64);
  if ((tid & 63) == 0) ssm[tid >> 6] = su;
  __syncthreads();
  if (tid == 0) {
    red[0] = g;
    red[1] = ssm[0] + ssm[1] + ssm[2] + ssm[3];
  }
  __syncthreads();
}

__device__ void segsum_bag(const ushortT* __restrict__ emb_in,
                           const float* __restrict__ s,
                           const float* __restrict__ red,
                           ushortT* __restrict__ emb_out, int b) {
  __shared__ float wsh[16];
  const int tid = threadIdx.x;
  __syncthreads();
  if (tid < 16) wsh[tid] = expf(s[b * 16 + tid] - red[0]) / red[1];
  __syncthreads();
  const int kc = tid >> 1, jj = (tid & 1) * 4;
  const ushortT* src =
      emb_in + (size_t)(b >> 1) * 32768 + kc * 256 + ((b & 1) * 16) * 8 + jj;
  f32x4 acc;
#pragma unroll
  for (int z = 0; z < 4; ++z) acc[z] = 0.f;
#pragma unroll
  for (int k = 0; k < 16; ++k) {
    u16x4 uu = *(const u16x4*)(src + k * 8);
    float w = wsh[k];
    acc[0] += bf2f(uu[0]) * w;
    acc[1] += bf2f(uu[1]) * w;
    acc[2] += bf2f(uu[2]) * w;
    acc[3] += bf2f(uu[3]) * w;
  }
  u16x4 o;
#pragma unroll
  for (int z = 0; z < 4; ++z) o[z] = f2bf(acc[z]);
  *(u16x4*)(emb_out + (size_t)(b >> 5) * 32768 + kc * 256 + (b & 31) * 8 + jj) =
      o;
}

__global__ __launch_bounds__(256, 2) void tail_kernel(
    const ushortT* __restrict__ emb1, const ushortT* __restrict__ BpA1,
    const ushortT* __restrict__ BpA2, const ushortT* __restrict__ BpA3,
    const float* __restrict__ a1b, const float* __restrict__ a1v,
    const float* __restrict__ a1vb, const float* __restrict__ a2b,
    const float* __restrict__ a2v, const float* __restrict__ a2vb,
    const float* __restrict__ a3b, const float* __restrict__ a3v,
    const float* __restrict__ a3vb, const float* __restrict__ u,
    float* __restrict__ s1, float* __restrict__ s2, float* __restrict__ s3,
    float* __restrict__ red1, float* __restrict__ red2,
    float* __restrict__ w3g, ushortT* __restrict__ emb2,
    ushortT* __restrict__ emb3, unsigned* __restrict__ ctr,
    float* __restrict__ zsum, float* __restrict__ out) {
  const int blk = blockIdx.x, tid = threadIdx.x;
  const unsigned NB = 512;

  // S0: att1 over 16384 rows (512 blocks x 32 rows)
  att32(emb1 + (size_t)blk * 32768, BpA1, a1b, a1v, a1vb[0], s1 + blk * 32);
  gsync(ctr + 0, NB);
  // S1: softmax reduce level 1
  if (blk == 0) smr_block(s1, 16384, red1);
  gsync(ctr + 1, NB);
  // S2: segsum level 1 (1024 bags)
  segsum_bag(emb1, s1, red1, emb2, blk * 2);
  segsum_bag(emb1, s1, red1, emb2, blk * 2 + 1);
  gsync(ctr + 2, NB);
  // S3: att2 over 1024 rows (32 blocks)
  if (blk < 32)
    att32(emb2 + (size_t)blk * 32768, BpA2, a2b, a2v, a2vb[0], s2 + blk * 32);
  gsync(ctr + 3, NB);
  // S4: softmax reduce level 2
  if (blk == 0) smr_block(s2, 1024, red2);
  gsync(ctr + 4, NB);
  // S5: segsum level 2 (64 bags)
  if (blk < 32) {
    segsum_bag(emb2, s2, red2, emb3, blk * 2);
    segsum_bag(emb2, s2, red2, emb3, blk * 2 + 1);
  }
  gsync(ctr + 5, NB);
  // S6: att3 over 64 rows (2 blocks)
  if (blk < 2)
    att32(emb3 + (size_t)blk * 32768, BpA3, a3b, a3v, a3vb[0], s3 + blk * 32);
  gsync(ctr + 6, NB);
  // S7: softmax level 3 -> w3g
  if (blk == 0) {
    __shared__ float m3s, s3s;
    if (tid == 0) {
      float m = s3[0];
      for (int i = 1; i < 64; ++i) m = fmaxf(m, s3[i]);
      float su = 0.f;
      for (int i = 0; i < 64; ++i) su += expf(s3[i] - m);
      m3s = m;
      s3s = su;
    }
    __syncthreads();
    if (tid < 64) w3g[tid] = expf(s3[tid] - m3s) / s3s;
    __syncthreads();
  }
  gsync(ctr + 7, NB);
  // S8: head partials: zsum += (w3 @ emb3)[k] * u[k]
  if (blk < 4) {
    int k = blk * 256 + tid;
    int kc = k >> 3, j = k & 7;
    float outer = 0.f;
#pragma unroll
    for (int b = 0; b < 64; ++b)
      outer += w3g[b] *
               bf2f(emb3[(size_t)(b >> 5) * 32768 + kc * 256 + (b & 31) * 8 + j]);
    float zp = outer * u[k];
#pragma unroll
    for (int off = 32; off; off >>= 1) zp += __shfl_xor(zp, off, 64);
    if ((tid & 63) == 0) atomicAdd(zsum, zp);
  }
  gsync(ctr + 8, NB);
  // S9: final sigmoid (cbdot = cls_b . out_W + out_b precomputed in u[1024])
  if (blk == 0 && tid == 0) out[0] = 1.f / (1.f + expf(-(zsum[0] + u[1024])));
}

// ---------------------------------------------------------------------------
extern "C" void kernel_launch(void* const* d_in, const int* in_sizes, int n_in,
                              void* d_out, int out_size, void* d_ws,
                              size_t ws_size, hipStream_t stream) {
  const float* x       = (const float*)d_in[0];
  const float* conv1_w = (const float*)d_in[1];
  const float* conv1_b = (const float*)d_in[2];
  const float* conv2_w = (const float*)d_in[3];
  const float* conv2_b = (const float*)d_in[4];
  const float* att1_W  = (const float*)d_in[5];
  const float* att1_b  = (const float*)d_in[6];
  const float* att1_v  = (const float*)d_in[7];
  const float* att1_vb = (const float*)d_in[8];
  const float* att2_W  = (const float*)d_in[9];
  const float* att2_b  = (const float*)d_in[10];
  const float* att2_v  = (const float*)d_in[11];
  const float* att2_vb = (const float*)d_in[12];
  const float* att3_W  = (const float*)d_in[13];
  const float* att3_b  = (const float*)d_in[14];
  const float* att3_v  = (const float*)d_in[15];
  const float* att3_vb = (const float*)d_in[16];
  const float* cls_W   = (const float*)d_in[17];
  const float* cls_b   = (const float*)d_in[18];
  const float* out_W   = (const float*)d_in[19];
  const float* out_b   = (const float*)d_in[20];

  char* p = (char*)d_ws;
  ushortT* emb1 = (ushortT*)p; p += (size_t)16384 * 1024 * 2;
  ushortT* Bp1  = (ushortT*)p; p += 2048;
  ushortT* Bp2  = (ushortT*)p; p += 102400;
  ushortT* BpA1 = (ushortT*)p; p += 524288;
  ushortT* BpA2 = (ushortT*)p; p += 524288;
  ushortT* BpA3 = (ushortT*)p; p += 524288;
  float* u      = (float*)p;   p += 8192;   // u[0..1023] + cbdot at u[1024]
  ushortT* emb2 = (ushortT*)p; p += (size_t)1024 * 1024 * 2;
  ushortT* emb3 = (ushortT*)p; p += 64 * 1024 * 2;
  float* s1     = (float*)p;   p += 16384 * 4;
  float* s2     = (float*)p;   p += 4096;
  float* s3     = (float*)p;   p += 256;
  float* red1   = (float*)p;   p += 256;
  float* red2   = (float*)p;   p += 256;
  float* w3g    = (float*)p;   p += 256;
  unsigned* ctr = (unsigned*)p; p += 64;    // 9 barrier counters
  float* zsum   = (float*)p;   p += 64;

  prepack_kernel<<<3533, 256, 0, stream>>>(conv1_w, conv2_w, att1_W, att2_W,
                                           att3_W, cls_W, cls_b, out_W, out_b,
                                           Bp1, Bp2, BpA1, BpA2, BpA3, u);
  fused_conv_mfma_kernel<<<4096, 256, 0, stream>>>(x, Bp1, conv1_b, Bp2,
                                                   conv2_b, emb1);
  hipMemsetAsync(ctr, 0, 128, stream);  // zero barrier counters + zsum
  tail_kernel<<<512, 256, 0, stream>>>(
      emb1, BpA1, BpA2, BpA3, att1_b, att1_v, att1_vb, att2_b, att2_v, att2_vb,
      att3_b, att3_v, att3_vb, u, s1, s2, s3, red1, red2, w3g, emb2, emb3, ctr,
      zsum, (float*)d_out);
}

// Round 7
// 577.778 us; speedup vs baseline: 2.0367x; 2.0367x over previous
//
#include <hip/hip_runtime.h>
#include <hip/hip_bf16.h>
#include <math.h>

typedef float f32x4 __attribute__((ext_vector_type(4)));
using bf16x8 = __attribute__((ext_vector_type(8))) short;
using f32x16 = __attribute__((ext_vector_type(16))) float;
typedef unsigned short ushortT;
using u16x4 = __attribute__((ext_vector_type(4))) unsigned short;

__device__ __forceinline__ ushortT f2bf(float f) {
  unsigned int u = __builtin_bit_cast(unsigned int, f);
  u = (u + 0x7FFFu + ((u >> 16) & 1u)) >> 16;
  return (ushortT)u;
}
__device__ __forceinline__ float bf2f(ushortT u) {
  return __builtin_bit_cast(float, (unsigned int)u << 16);
}
__device__ __forceinline__ void gload_lds16(const void* gsrc, void* ldst) {
  __builtin_amdgcn_global_load_lds(
      (const __attribute__((address_space(1))) unsigned int*)gsrc,
      (__attribute__((address_space(3))) unsigned int*)ldst, 16, 0, 0);
}

// emb tiled layout: emb_t[(row>>5)*32768 + kc*256 + (row&31)*8 + j], k=kc*8+j

// ---------------------------------------------------------------------------
// Prepack: bf16 MFMA fragment layouts + u = cls_W @ out_W + cbdot scalar.
// ---------------------------------------------------------------------------
__global__ __launch_bounds__(256) void prepack_kernel(
    const float* __restrict__ w1, const float* __restrict__ w2,
    const float* __restrict__ aW1, const float* __restrict__ aW2,
    const float* __restrict__ aW3, const float* __restrict__ cls_W,
    const float* __restrict__ cls_b, const float* __restrict__ out_W,
    const float* __restrict__ out_b, ushortT* __restrict__ Bp1,
    ushortT* __restrict__ Bp2, ushortT* __restrict__ BpA1,
    ushortT* __restrict__ BpA2, ushortT* __restrict__ BpA3,
    float* __restrict__ u) {
  const int i = blockIdx.x * 256 + threadIdx.x;
  const int n1 = 1024, n2 = 51200, nA = 262144, nU = 65536;
  if (i < n1) {
    int nt = i >> 9, l = (i >> 3) & 63, j = i & 7;
    int tap = ((l >> 4) << 3) + j, ch = nt * 16 + (l & 15);
    Bp1[i] = (tap < 25) ? f2bf(w1[tap * 32 + ch]) : (ushortT)0;
  } else if (i < n1 + n2) {
    int t = i - n1;
    int co = t & 63, k = t >> 6;  // coalesced read over co
    int s = k >> 4, hi = (k >> 3) & 1, j = k & 7;
    int nt = co >> 5, l31 = co & 31;
    Bp2[(s * 2 + nt) * 512 + (hi * 32 + l31) * 8 + j] = f2bf(w2[k * 64 + co]);
  } else if (i < n1 + n2 + 3 * nA) {
    int t = i - n1 - n2;
    int m = t >> 18, r = t & (nA - 1);
    const float* aW = (m == 0) ? aW1 : ((m == 1) ? aW2 : aW3);
    ushortT* dst = (m == 0) ? BpA1 : ((m == 1) ? BpA2 : BpA3);
    int col = r & 255, k = r >> 8;  // coalesced read over col
    int nt = col >> 5, l31 = col & 31;
    int s = k >> 4, hi = (k >> 3) & 1, j = k & 7;
    dst[nt * 32768 + s * 512 + (hi * 32 + l31) * 8 + j] =
        f2bf(aW[k * 256 + col]);
  } else if (i < n1 + n2 + 3 * nA + nU) {
    int t = i - (n1 + n2 + 3 * nA);
    int k = t >> 6, lane = t & 63;
    float p = 0.f;
#pragma unroll
    for (int j = 0; j < 8; ++j) {
      int jj = lane + j * 64;
      p += cls_W[k * 512 + jj] * out_W[jj];
    }
#pragma unroll
    for (int off = 32; off; off >>= 1) p += __shfl_xor(p, off, 64);
    if (lane == 0) u[k] = p;
  } else if (i < n1 + n2 + 3 * nA + nU + 64) {
    int lane = i - (n1 + n2 + 3 * nA + nU);
    float p = 0.f;
#pragma unroll
    for (int j = 0; j < 8; ++j) {
      int jj = lane * 8 + j;
      p += cls_b[jj] * out_W[jj];
    }
#pragma unroll
    for (int off = 32; off; off >>= 1) p += __shfl_xor(p, off, 64);
    if (lane == 0) u[1024] = p + out_b[0];
  }
}

// ---------------------------------------------------------------------------
// Fused conv: 4 instances/block, one wave per instance. conv2 B double-
// buffered in LDS (4 K-steps per chunk). h1 stride 36 (16 bank-starts).
// ---------------------------------------------------------------------------
#define PADW 36
__global__ __launch_bounds__(256, 2) void fused_conv_mfma_kernel(
    const float* __restrict__ x, const ushortT* __restrict__ Bp1,
    const float* __restrict__ b1g, const ushortT* __restrict__ Bp2,
    const float* __restrict__ b2g, ushortT* __restrict__ emb1) {
  __shared__ ushortT h1s[4][144 * PADW];        // 41472 B
  __shared__ __align__(16) char uni[4 * 2080];  // xs / epi slabs
  __shared__ ushortT Bbuf[2][4096];             // 2 x 8KB chunks (4 K-steps)

  const int tid = threadIdx.x, wv = tid >> 6, lane = tid & 63;
  const int inst = blockIdx.x * 4 + wv;
  ushortT* xs = (ushortT*)(uni + wv * 2080);
  ushortT* h1w = &h1s[wv][0];

  // stage conv2 B chunk 0 (overlaps conv1)
  {
    int base = wv * 2048;
    gload_lds16((const char*)Bp2 + base + lane * 16, (char*)&Bbuf[0][0] + base);
    gload_lds16((const char*)Bp2 + base + 1024 + lane * 16,
                (char*)&Bbuf[0][0] + base + 1024);
  }

  // x -> bf16 LDS (wave-private)
  {
    const float* xg = x + (size_t)inst * 784;
#pragma unroll
    for (int t = 0; t < 4; ++t) {
      int g = lane + t * 64;
      if (g < 196) {
        f32x4 v = *(const f32x4*)&xg[g * 4];
        u16x4 o;
#pragma unroll
        for (int z = 0; z < 4; ++z) o[z] = f2bf(v[z]);
        *(u16x4*)&xs[g * 4] = o;
      }
    }
  }

  // ---------------- conv1 via MFMA 16x16x32 (wave-private) ----------------
  {
    const int arow = lane & 15, kg = lane >> 4;
    int koff[8], kval[8];
#pragma unroll
    for (int j = 0; j < 8; ++j) {
      int tap = kg * 8 + j;
      int ky = (tap * 13) >> 6;
      int kx = tap - ky * 5;
      kval[j] = (tap < 25);
      koff[j] = kval[j] ? (ky * 28 + kx) : 0;
    }
    bf16x8 w1f0 = *(const bf16x8*)&Bp1[lane * 8];
    bf16x8 w1f1 = *(const bf16x8*)&Bp1[(64 + lane) * 8];
    const float bA = b1g[arow], bB = b1g[16 + arow];

#pragma unroll 4
    for (int g = 0; g < 36; ++g) {
      int R = g * 16 + arow;
      int q = R >> 2, quad = R & 3;
      int qy = q / 12, qx = q - qy * 12;
      int base = (2 * qy + (quad >> 1)) * 28 + 2 * qx + (quad & 1);
      bf16x8 a;
#pragma unroll
      for (int j = 0; j < 8; ++j) {
        ushortT vv = xs[base + koff[j]];
        a[j] = (short)(kval[j] ? vv : (ushortT)0);
      }
      f32x4 c0, c1;
#pragma unroll
      for (int z = 0; z < 4; ++z) { c0[z] = 0.f; c1[z] = 0.f; }
      c0 = __builtin_amdgcn_mfma_f32_16x16x32_bf16(a, w1f0, c0, 0, 0, 0);
      c1 = __builtin_amdgcn_mfma_f32_16x16x32_bf16(a, w1f1, c1, 0, 0, 0);
      int qo = g * 4 + kg;
      float m0 = fmaxf(fmaxf(c0[0], c0[1]), fmaxf(c0[2], c0[3]));
      float m1 = fmaxf(fmaxf(c1[0], c1[1]), fmaxf(c1[2], c1[3]));
      h1w[qo * PADW + arow] = f2bf(fmaxf(m0 + bA, 0.f));
      h1w[qo * PADW + 16 + arow] = f2bf(fmaxf(m1 + bB, 0.f));
    }
  }
  __syncthreads();  // h1 done; chunk 0 landed (barrier drains vmcnt)

  // ---------------- conv2 via MFMA 32x32x16 (LDS dbuf B) ------------------
  {
    const int hi = lane >> 5, l31 = lane & 31;
    int rowbase0, rowbase1;
    {
      int q2 = l31 >> 2, quad2 = l31 & 3;
      rowbase0 = (2 * (q2 >> 2) + (quad2 >> 1)) * 12 + 2 * (q2 & 3) + (quad2 & 1);
      q2 = (32 + l31) >> 2;
      rowbase1 = (2 * (q2 >> 2) + (quad2 >> 1)) * 12 + 2 * (q2 & 3) + (quad2 & 1);
    }
    const int ab0 = rowbase0 * PADW + hi * 8;
    const int ab1 = rowbase1 * PADW + hi * 8;

    f32x16 a00, a01, a10, a11;
#pragma unroll
    for (int z = 0; z < 16; ++z) { a00[z] = 0.f; a01[z] = 0.f; a10[z] = 0.f; a11[z] = 0.f; }

    for (int c = 0; c < 13; ++c) {
      if (c < 12) {  // stage chunk c+1
        char* dstb = (char*)&Bbuf[(c + 1) & 1][0];
        const char* srcb = (const char*)Bp2 + (size_t)(c + 1) * 8192;
        if (c + 1 < 12) {
          gload_lds16(srcb + wv * 2048 + lane * 16, dstb + wv * 2048);
          gload_lds16(srcb + wv * 2048 + 1024 + lane * 16,
                      dstb + wv * 2048 + 1024);
        } else {
          gload_lds16(srcb + wv * 1024 + lane * 16, dstb + wv * 1024);
        }
      }
      const ushortT* bb = &Bbuf[c & 1][0];
      const int ns = (c < 12) ? 4 : 2;
#pragma unroll
      for (int i = 0; i < 4; ++i) {
        if (i < ns) {
          int s = c * 4 + i;
          int tap = s >> 1;
          int ky = (tap * 13) >> 6, kx = tap - ky * 5;
          int aoff = (ky * 12 + kx) * PADW + ((s & 1) << 4);
          bf16x8 bf0 = *(const bf16x8*)&bb[i * 1024 + lane * 8];
          bf16x8 bf1 = *(const bf16x8*)&bb[i * 1024 + 512 + lane * 8];
          bf16x8 af0 = *(const bf16x8*)&h1w[ab0 + aoff];
          bf16x8 af1 = *(const bf16x8*)&h1w[ab1 + aoff];
          a00 = __builtin_amdgcn_mfma_f32_32x32x16_bf16(af0, bf0, a00, 0, 0, 0);
          a01 = __builtin_amdgcn_mfma_f32_32x32x16_bf16(af0, bf1, a01, 0, 0, 0);
          a10 = __builtin_amdgcn_mfma_f32_32x32x16_bf16(af1, bf0, a10, 0, 0, 0);
          a11 = __builtin_amdgcn_mfma_f32_32x32x16_bf16(af1, bf1, a11, 0, 0, 0);
        }
      }
      __syncthreads();
    }

    // epilogue: bias + pool + relu -> wave-private epi slab (flat k = p*64+c)
    ushortT* epi = (ushortT*)(uni + wv * 2080);
    const float b2_0 = b2g[l31], b2_1 = b2g[32 + l31];
#pragma unroll
    for (int rg = 0; rg < 4; ++rg) {
      float m00 = fmaxf(fmaxf(a00[rg * 4], a00[rg * 4 + 1]),
                        fmaxf(a00[rg * 4 + 2], a00[rg * 4 + 3]));
      float m01 = fmaxf(fmaxf(a01[rg * 4], a01[rg * 4 + 1]),
                        fmaxf(a01[rg * 4 + 2], a01[rg * 4 + 3]));
      float m10 = fmaxf(fmaxf(a10[rg * 4], a10[rg * 4 + 1]),
                        fmaxf(a10[rg * 4 + 2], a10[rg * 4 + 3]));
      float m11 = fmaxf(fmaxf(a11[rg * 4], a11[rg * 4 + 1]),
                        fmaxf(a11[rg * 4 + 2], a11[rg * 4 + 3]));
      int p0 = 2 * rg + hi, p1 = 8 + 2 * rg + hi;
      epi[p0 * 64 + l31] = f2bf(fmaxf(m00 + b2_0, 0.f));
      epi[p0 * 64 + 32 + l31] = f2bf(fmaxf(m01 + b2_1, 0.f));
      epi[p1 * 64 + l31] = f2bf(fmaxf(m10 + b2_0, 0.f));
      epi[p1 * 64 + 32 + l31] = f2bf(fmaxf(m11 + b2_1, 0.f));
    }
  }
  __syncthreads();

  // cooperative tiled store
  {
    const int bid = blockIdx.x;
    ushortT* dstbase = emb1 + (size_t)(bid >> 3) * 32768;
    const int instoff = 4 * (bid & 7);
#pragma unroll
    for (int z = 0; z < 2; ++z) {
      int kchunk = (tid >> 2) + z * 64;
      int i = tid & 3;
      bf16x8 vv = *(const bf16x8*)(uni + i * 2080 + kchunk * 16);
      *(bf16x8*)&dstbase[(size_t)kchunk * 256 + (instoff + i) * 8] = vv;
    }
  }
}

// ---------------------------------------------------------------------------
// Persistent fused tail. Grid barrier: atomic arrival counter + read-only
// flag polling (agent-scope loads; polls don't contend with arrivals).
// Softmax folded as exp(s)/sum (s in (0,1) -> no max subtraction needed).
// ---------------------------------------------------------------------------
__device__ __forceinline__ void gbar(unsigned* ctr, unsigned* flag,
                                     unsigned nb) {
  __syncthreads();
  if (threadIdx.x == 0) {
    __threadfence();
    unsigned old = __hip_atomic_fetch_add(ctr, 1u, __ATOMIC_ACQ_REL,
                                          __HIP_MEMORY_SCOPE_AGENT);
    if (old == nb - 1) {
      __hip_atomic_store(flag, 1u, __ATOMIC_RELEASE, __HIP_MEMORY_SCOPE_AGENT);
    } else {
      while (__hip_atomic_load(flag, __ATOMIC_ACQUIRE,
                               __HIP_MEMORY_SCOPE_AGENT) == 0)
        __builtin_amdgcn_s_sleep(1);
    }
    __threadfence();
  }
  __syncthreads();
}

// 32-row attention tile: s_out[r] = exp(sigmoid(tanh(row@W+b)@v+vb));
// block partial sum of exp atomically added to *sum.
__device__ void att32exp(const ushortT* __restrict__ atile,
                         const ushortT* __restrict__ Bp,
                         const float* __restrict__ bias,
                         const float* __restrict__ v, float vb0,
                         float* __restrict__ s_out, float* __restrict__ sum) {
  __shared__ float part[32][4];
  const int tid = threadIdx.x, wv = tid >> 6, lane = tid & 63;
  const int hi = lane >> 5, l31 = lane & 31;
  const ushortT* ap = atile + hi * 256 + l31 * 8;
  const ushortT* bp0 = Bp + (size_t)(2 * wv) * 32768 + (size_t)lane * 8;
  const ushortT* bp1 = bp0 + 32768;

  f32x16 a0, a1;
#pragma unroll
  for (int z = 0; z < 16; ++z) { a0[z] = 0.f; a1[z] = 0.f; }

#pragma unroll 8
  for (int s = 0; s < 64; ++s) {
    bf16x8 af = *(const bf16x8*)(ap + s * 512);
    bf16x8 b0 = *(const bf16x8*)(bp0 + s * 512);
    bf16x8 b1 = *(const bf16x8*)(bp1 + s * 512);
    a0 = __builtin_amdgcn_mfma_f32_32x32x16_bf16(af, b0, a0, 0, 0, 0);
    a1 = __builtin_amdgcn_mfma_f32_32x32x16_bf16(af, b1, a1, 0, 0, 0);
  }

  const int c0 = wv * 64 + l31, c1 = c0 + 32;
  const float bc0 = bias[c0], vc0 = v[c0];
  const float bc1 = bias[c1], vc1 = v[c1];
#pragma unroll
  for (int r = 0; r < 16; ++r) {
    float p = tanhf(a0[r] + bc0) * vc0 + tanhf(a1[r] + bc1) * vc1;
#pragma unroll
    for (int off = 16; off >= 1; off >>= 1) p += __shfl_xor(p, off, 64);
    if (l31 == 0) part[(r & 3) + 8 * (r >> 2) + 4 * hi][wv] = p;
  }
  __syncthreads();
  if (tid < 32) {
    float ss = vb0 + part[tid][0] + part[tid][1] + part[tid][2] + part[tid][3];
    float e = expf(1.f / (1.f + expf(-ss)));
    s_out[tid] = e;
#pragma unroll
    for (int off = 16; off >= 1; off >>= 1) e += __shfl_xor(e, off, 64);
    if (tid == 0) atomicAdd(sum, e);
  }
  __syncthreads();
}

// emb_out[bag b] = sum_k (sexp[b*16+k]*inv) * emb_in[row b*16+k]   (tiled IO)
__device__ void segsum_bag(const ushortT* __restrict__ emb_in,
                           const float* __restrict__ sexp, float inv,
                           ushortT* __restrict__ emb_out, int b) {
  __shared__ float wsh[16];
  const int tid = threadIdx.x;
  __syncthreads();
  if (tid < 16) wsh[tid] = sexp[b * 16 + tid] * inv;
  __syncthreads();
  const int kc = tid >> 1, jj = (tid & 1) * 4;
  const ushortT* src =
      emb_in + (size_t)(b >> 1) * 32768 + kc * 256 + ((b & 1) * 16) * 8 + jj;
  f32x4 acc;
#pragma unroll
  for (int z = 0; z < 4; ++z) acc[z] = 0.f;
#pragma unroll
  for (int k = 0; k < 16; ++k) {
    u16x4 uu = *(const u16x4*)(src + k * 8);
    float w = wsh[k];
    acc[0] += bf2f(uu[0]) * w;
    acc[1] += bf2f(uu[1]) * w;
    acc[2] += bf2f(uu[2]) * w;
    acc[3] += bf2f(uu[3]) * w;
  }
  u16x4 o;
#pragma unroll
  for (int z = 0; z < 4; ++z) o[z] = f2bf(acc[z]);
  *(u16x4*)(emb_out + (size_t)(b >> 5) * 32768 + kc * 256 + (b & 31) * 8 + jj) =
      o;
}

__global__ __launch_bounds__(256, 2) void tail_kernel(
    const ushortT* __restrict__ emb1, const ushortT* __restrict__ BpA1,
    const ushortT* __restrict__ BpA2, const ushortT* __restrict__ BpA3,
    const float* __restrict__ a1b, const float* __restrict__ a1v,
    const float* __restrict__ a1vb, const float* __restrict__ a2b,
    const float* __restrict__ a2v, const float* __restrict__ a2vb,
    const float* __restrict__ a3b, const float* __restrict__ a3v,
    const float* __restrict__ a3vb, const float* __restrict__ u,
    float* __restrict__ s1, float* __restrict__ s2, float* __restrict__ s3,
    ushortT* __restrict__ emb2, ushortT* __restrict__ emb3,
    unsigned* __restrict__ ctrl, float* __restrict__ out) {
  const int blk = blockIdx.x, tid = threadIdx.x;
  unsigned* ctr = ctrl;            // [0..5] arrival counters
  unsigned* flg = ctrl + 8;        // [0..5] release flags
  float* fs = (float*)(ctrl + 16); // fs[0..2]=sum1..3, fs[3]=zsum

  // S0: att1 (512 blocks x 32 rows) + exp + global sum
  att32exp(emb1 + (size_t)blk * 32768, BpA1, a1b, a1v, a1vb[0], s1 + blk * 32,
           fs + 0);
  gbar(ctr + 0, flg + 0, 512);
  // S1: segsum level 1 (1024 bags / 512 blocks)
  {
    float inv = 1.f / fs[0];
    segsum_bag(emb1, s1, inv, emb2, blk * 2);
    segsum_bag(emb1, s1, inv, emb2, blk * 2 + 1);
  }
  gbar(ctr + 1, flg + 1, 512);
  if (blk >= 32) return;
  // S2: att2 (32 blocks x 32 rows)
  att32exp(emb2 + (size_t)blk * 32768, BpA2, a2b, a2v, a2vb[0], s2 + blk * 32,
           fs + 1);
  gbar(ctr + 2, flg + 2, 32);
  // S3: segsum level 2 (64 bags / 32 blocks)
  {
    float inv = 1.f / fs[1];
    segsum_bag(emb2, s2, inv, emb3, blk * 2);
    segsum_bag(emb2, s2, inv, emb3, blk * 2 + 1);
  }
  gbar(ctr + 3, flg + 3, 32);
  if (blk >= 4) return;
  // S4: att3 (2 blocks x 32 rows)
  if (blk < 2)
    att32exp(emb3 + (size_t)blk * 32768, BpA3, a3b, a3v, a3vb[0], s3 + blk * 32,
             fs + 2);
  gbar(ctr + 4, flg + 4, 4);
  // S5: head partials: zsum += ((w3 @ emb3) * u)[k]
  {
    float inv3 = 1.f / fs[2];
    int k = blk * 256 + tid;
    int kc = k >> 3, j = k & 7;
    float outer = 0.f;
#pragma unroll
    for (int b = 0; b < 64; ++b)
      outer += s3[b] *
               bf2f(emb3[(size_t)(b >> 5) * 32768 + kc * 256 + (b & 31) * 8 + j]);
    float zp = outer * inv3 * u[k];
#pragma unroll
    for (int off = 32; off; off >>= 1) zp += __shfl_xor(zp, off, 64);
    if ((tid & 63) == 0) atomicAdd(fs + 3, zp);
  }
  gbar(ctr + 5, flg + 5, 4);
  // S6: final sigmoid (cbdot = cls_b . out_W + out_b precomputed in u[1024])
  if (blk == 0 && tid == 0) out[0] = 1.f / (1.f + expf(-(fs[3] + u[1024])));
}

// ---------------------------------------------------------------------------
extern "C" void kernel_launch(void* const* d_in, const int* in_sizes, int n_in,
                              void* d_out, int out_size, void* d_ws,
                              size_t ws_size, hipStream_t stream) {
  const float* x       = (const float*)d_in[0];
  const float* conv1_w = (const float*)d_in[1];
  const float* conv1_b = (const float*)d_in[2];
  const float* conv2_w = (const float*)d_in[3];
  const float* conv2_b = (const float*)d_in[4];
  const float* att1_W  = (const float*)d_in[5];
  const float* att1_b  = (const float*)d_in[6];
  const float* att1_v  = (const float*)d_in[7];
  const float* att1_vb = (const float*)d_in[8];
  const float* att2_W  = (const float*)d_in[9];
  const float* att2_b  = (const float*)d_in[10];
  const float* att2_v  = (const float*)d_in[11];
  const float* att2_vb = (const float*)d_in[12];
  const float* att3_W  = (const float*)d_in[13];
  const float* att3_b  = (const float*)d_in[14];
  const float* att3_v  = (const float*)d_in[15];
  const float* att3_vb = (const float*)d_in[16];
  const float* cls_W   = (const float*)d_in[17];
  const float* cls_b   = (const float*)d_in[18];
  const float* out_W   = (const float*)d_in[19];
  const float* out_b   = (const float*)d_in[20];

  char* p = (char*)d_ws;
  ushortT* emb1 = (ushortT*)p; p += (size_t)16384 * 1024 * 2;
  ushortT* Bp1  = (ushortT*)p; p += 2048;
  ushortT* Bp2  = (ushortT*)p; p += 102400;
  ushortT* BpA1 = (ushortT*)p; p += 524288;
  ushortT* BpA2 = (ushortT*)p; p += 524288;
  ushortT* BpA3 = (ushortT*)p; p += 524288;
  float* u      = (float*)p;   p += 8192;   // u[0..1023] + cbdot at u[1024]
  ushortT* emb2 = (ushortT*)p; p += (size_t)1024 * 1024 * 2;
  ushortT* emb3 = (ushortT*)p; p += 64 * 1024 * 2;
  float* s1     = (float*)p;   p += 16384 * 4;
  float* s2     = (float*)p;   p += 4096;
  float* s3     = (float*)p;   p += 256;
  unsigned* ctrl = (unsigned*)p; p += 256;  // ctr[8] | flg[8] | fs[4]

  prepack_kernel<<<3533, 256, 0, stream>>>(conv1_w, conv2_w, att1_W, att2_W,
                                           att3_W, cls_W, cls_b, out_W, out_b,
                                           Bp1, Bp2, BpA1, BpA2, BpA3, u);
  fused_conv_mfma_kernel<<<4096, 256, 0, stream>>>(x, Bp1, conv1_b, Bp2,
                                                   conv2_b, emb1);
  hipMemsetAsync(ctrl, 0, 256, stream);  // zero barriers + sums
  tail_kernel<<<512, 256, 0, stream>>>(
      emb1, BpA1, BpA2, BpA3, att1_b, att1_v, att1_vb, att2_b, att2_v, att2_vb,
      att3_b, att3_v, att3_vb, u, s1, s2, s3, emb2, emb3, ctrl,
      (float*)d_out);
}

// Round 8
// 453.107 us; speedup vs baseline: 2.5970x; 1.2751x over previous
//
#include <hip/hip_runtime.h>
#include <hip/hip_bf16.h>
#include <math.h>

typedef float f32x4 __attribute__((ext_vector_type(4)));
using bf16x8 = __attribute__((ext_vector_type(8))) short;
using f32x16 = __attribute__((ext_vector_type(16))) float;
typedef unsigned short ushortT;
using u16x4 = __attribute__((ext_vector_type(4))) unsigned short;

__device__ __forceinline__ ushortT f2bf(float f) {
  unsigned int u = __builtin_bit_cast(unsigned int, f);
  u = (u + 0x7FFFu + ((u >> 16) & 1u)) >> 16;
  return (ushortT)u;
}
__device__ __forceinline__ float bf2f(ushortT u) {
  return __builtin_bit_cast(float, (unsigned int)u << 16);
}
__device__ __forceinline__ void gload_lds16(const void* gsrc, void* ldst) {
  __builtin_amdgcn_global_load_lds(
      (const __attribute__((address_space(1))) unsigned int*)gsrc,
      (__attribute__((address_space(3))) unsigned int*)ldst, 16, 0, 0);
}

// ---------------------------------------------------------------------------
// Prepack: bf16 MFMA fragment layouts + u = cls_W @ out_W + cbdot at u[1024].
// Bp2 [s*2+nt][l][j] = w2[k][co]  k=s*16+(l>>5)*8+j, co=nt*32+(l&31)
// BpA [nt][s][l][j]  = W [k][col] k=s*16+(l>>5)*8+j, col=nt*32+(l&31)
// ---------------------------------------------------------------------------
__global__ __launch_bounds__(256) void prepack_kernel(
    const float* __restrict__ w1, const float* __restrict__ w2,
    const float* __restrict__ aW1, const float* __restrict__ aW2,
    const float* __restrict__ aW3, const float* __restrict__ cls_W,
    const float* __restrict__ cls_b, const float* __restrict__ out_W,
    const float* __restrict__ out_b, ushortT* __restrict__ Bp1,
    ushortT* __restrict__ Bp2, ushortT* __restrict__ BpA1,
    ushortT* __restrict__ BpA2, ushortT* __restrict__ BpA3,
    float* __restrict__ u) {
  const int i = blockIdx.x * 256 + threadIdx.x;
  const int n1 = 1024, n2 = 51200, nA = 262144, nU = 65536;
  if (i < n1) {
    int nt = i >> 9, l = (i >> 3) & 63, j = i & 7;
    int tap = ((l >> 4) << 3) + j, ch = nt * 16 + (l & 15);
    Bp1[i] = (tap < 25) ? f2bf(w1[tap * 32 + ch]) : (ushortT)0;
  } else if (i < n1 + n2) {
    int t = i - n1;
    int co = t & 63, k = t >> 6;  // coalesced read over co
    int s = k >> 4, hi = (k >> 3) & 1, j = k & 7;
    int nt = co >> 5, l31 = co & 31;
    Bp2[(s * 2 + nt) * 512 + (hi * 32 + l31) * 8 + j] = f2bf(w2[k * 64 + co]);
  } else if (i < n1 + n2 + 3 * nA) {
    int t = i - n1 - n2;
    int m = t >> 18, r = t & (nA - 1);
    const float* aW = (m == 0) ? aW1 : ((m == 1) ? aW2 : aW3);
    ushortT* dst = (m == 0) ? BpA1 : ((m == 1) ? BpA2 : BpA3);
    int col = r & 255, k = r >> 8;  // coalesced read over col
    int nt = col >> 5, l31 = col & 31;
    int s = k >> 4, hi = (k >> 3) & 1, j = k & 7;
    dst[nt * 32768 + s * 512 + (hi * 32 + l31) * 8 + j] =
        f2bf(aW[k * 256 + col]);
  } else if (i < n1 + n2 + 3 * nA + nU) {
    int t = i - (n1 + n2 + 3 * nA);
    int k = t >> 6, lane = t & 63;
    float p = 0.f;
#pragma unroll
    for (int j = 0; j < 8; ++j) {
      int jj = lane + j * 64;
      p += cls_W[k * 512 + jj] * out_W[jj];
    }
#pragma unroll
    for (int off = 32; off; off >>= 1) p += __shfl_xor(p, off, 64);
    if (lane == 0) u[k] = p;
  } else if (i < n1 + n2 + 3 * nA + nU + 64) {
    int lane = i - (n1 + n2 + 3 * nA + nU);
    float p = 0.f;
#pragma unroll
    for (int j = 0; j < 8; ++j) {
      int jj = lane * 8 + j;
      p += cls_b[jj] * out_W[jj];
    }
#pragma unroll
    for (int off = 32; off; off >>= 1) p += __shfl_xor(p, off, 64);
    if (lane == 0) u[1024] = p + out_b[0];
  }
}

// ---------------------------------------------------------------------------
// Fused conv — VERBATIM round-3 config (measured 186us): 4 instances/block,
// one wave per instance, PADW=40, LDS-dbuf B, direct row-major emb1 store.
// ---------------------------------------------------------------------------
#define PADW 40
__global__ __launch_bounds__(256, 2) void fused_conv_mfma_kernel(
    const float* __restrict__ x, const ushortT* __restrict__ Bp1,
    const float* __restrict__ b1g, const ushortT* __restrict__ Bp2,
    const float* __restrict__ b2g, ushortT* __restrict__ emb1) {
  __shared__ ushortT xs[4][784];
  __shared__ ushortT h1s[4][144 * PADW];
  __shared__ ushortT Bbuf[2][4096];  // 8KB chunks = 4 K-steps

  const int tid = threadIdx.x, wv = tid >> 6, lane = tid & 63;
  const int inst = blockIdx.x * 4 + wv;

  // stage conv2 B chunk 0 (overlaps conv1)
  {
    int base = wv * 2048;
    gload_lds16((const char*)Bp2 + base + lane * 16, (char*)&Bbuf[0][0] + base);
    gload_lds16((const char*)Bp2 + base + 1024 + lane * 16,
                (char*)&Bbuf[0][0] + base + 1024);
  }

  // x -> bf16 LDS (wave-local instance)
  const float* xg = x + (size_t)inst * 784;
  for (int i = lane; i < 784; i += 64) xs[wv][i] = f2bf(xg[i]);
  __syncthreads();

  // ---------------- conv1 via MFMA (wave owns instance) ----------------
  {
    const int arow = lane & 15, kg = lane >> 4;
    int koff[8], kval[8];
#pragma unroll
    for (int j = 0; j < 8; ++j) {
      int tap = kg * 8 + j;
      int ky = (tap * 13) >> 6;
      int kx = tap - ky * 5;
      kval[j] = (tap < 25);
      koff[j] = kval[j] ? (ky * 28 + kx) : 0;
    }
    bf16x8 w1f0 = *(const bf16x8*)&Bp1[lane * 8];
    bf16x8 w1f1 = *(const bf16x8*)&Bp1[(64 + lane) * 8];
    const float bA = b1g[arow], bB = b1g[16 + arow];

#pragma unroll 4
    for (int g = 0; g < 36; ++g) {
      int R = g * 16 + arow;
      int q = R >> 2, quad = R & 3;
      int qy = q / 12, qx = q - qy * 12;
      int base = (2 * qy + (quad >> 1)) * 28 + 2 * qx + (quad & 1);
      bf16x8 a;
#pragma unroll
      for (int j = 0; j < 8; ++j) {
        ushortT vv = xs[wv][base + koff[j]];
        a[j] = (short)(kval[j] ? vv : (ushortT)0);
      }
      f32x4 c0, c1;
#pragma unroll
      for (int z = 0; z < 4; ++z) { c0[z] = 0.f; c1[z] = 0.f; }
      c0 = __builtin_amdgcn_mfma_f32_16x16x32_bf16(a, w1f0, c0, 0, 0, 0);
      c1 = __builtin_amdgcn_mfma_f32_16x16x32_bf16(a, w1f1, c1, 0, 0, 0);
      int qo = g * 4 + kg;
      float m0 = fmaxf(fmaxf(c0[0], c0[1]), fmaxf(c0[2], c0[3]));
      float m1 = fmaxf(fmaxf(c1[0], c1[1]), fmaxf(c1[2], c1[3]));
      h1s[wv][qo * PADW + arow] = f2bf(fmaxf(m0 + bA, 0.f));
      h1s[wv][qo * PADW + 16 + arow] = f2bf(fmaxf(m1 + bB, 0.f));
    }
  }
  __syncthreads();

  // ---------------- conv2 via MFMA (wave owns instance, 64x64) -----------
  {
    const int hi = lane >> 5, l31 = lane & 31;
    int rowbase0, rowbase1;
    {
      int q2 = l31 >> 2, quad2 = l31 & 3;
      rowbase0 = (2 * (q2 >> 2) + (quad2 >> 1)) * 12 + 2 * (q2 & 3) + (quad2 & 1);
      q2 = (32 + l31) >> 2;
      rowbase1 = (2 * (q2 >> 2) + (quad2 >> 1)) * 12 + 2 * (q2 & 3) + (quad2 & 1);
    }
    const ushortT* h1w = &h1s[wv][0];

    f32x16 a00, a01, a10, a11;
#pragma unroll
    for (int z = 0; z < 16; ++z) { a00[z] = 0.f; a01[z] = 0.f; a10[z] = 0.f; a11[z] = 0.f; }

    for (int c = 0; c < 13; ++c) {
      if (c < 12) {  // stage chunk c+1
        char* dstb = (char*)&Bbuf[(c + 1) & 1][0];
        const char* srcb = (const char*)Bp2 + (size_t)(c + 1) * 8192;
        if (c + 1 < 12) {
          gload_lds16(srcb + wv * 2048 + lane * 16, dstb + wv * 2048);
          gload_lds16(srcb + wv * 2048 + 1024 + lane * 16,
                      dstb + wv * 2048 + 1024);
        } else {
          gload_lds16(srcb + wv * 1024 + lane * 16, dstb + wv * 1024);
        }
      }
      const ushortT* bb = &Bbuf[c & 1][0];
      const int ns = (c < 12) ? 4 : 2;
#pragma unroll
      for (int i = 0; i < 4; ++i) {
        if (i < ns) {
          int s = c * 4 + i;
          int tap = s >> 1;
          int ky = (tap * 13) >> 6, kx = tap - ky * 5;
          int aoff = (ky * 12 + kx) * PADW + ((s & 1) << 4) + hi * 8;
          bf16x8 bf0 = *(const bf16x8*)&bb[i * 1024 + lane * 8];
          bf16x8 bf1 = *(const bf16x8*)&bb[i * 1024 + 512 + lane * 8];
          bf16x8 af0 = *(const bf16x8*)&h1w[rowbase0 * PADW + aoff];
          bf16x8 af1 = *(const bf16x8*)&h1w[rowbase1 * PADW + aoff];
          a00 = __builtin_amdgcn_mfma_f32_32x32x16_bf16(af0, bf0, a00, 0, 0, 0);
          a01 = __builtin_amdgcn_mfma_f32_32x32x16_bf16(af0, bf1, a01, 0, 0, 0);
          a10 = __builtin_amdgcn_mfma_f32_32x32x16_bf16(af1, bf0, a10, 0, 0, 0);
          a11 = __builtin_amdgcn_mfma_f32_32x32x16_bf16(af1, bf1, a11, 0, 0, 0);
        }
      }
      __syncthreads();
    }

    // epilogue: bias + 4-reg pool + relu -> emb1 bf16 (row-major)
    const float b2_0 = b2g[l31], b2_1 = b2g[32 + l31];
    ushortT* erow = emb1 + (size_t)inst * 1024;
#pragma unroll
    for (int rg = 0; rg < 4; ++rg) {
      float m00 = fmaxf(fmaxf(a00[rg * 4], a00[rg * 4 + 1]),
                        fmaxf(a00[rg * 4 + 2], a00[rg * 4 + 3]));
      float m01 = fmaxf(fmaxf(a01[rg * 4], a01[rg * 4 + 1]),
                        fmaxf(a01[rg * 4 + 2], a01[rg * 4 + 3]));
      float m10 = fmaxf(fmaxf(a10[rg * 4], a10[rg * 4 + 1]),
                        fmaxf(a10[rg * 4 + 2], a10[rg * 4 + 3]));
      float m11 = fmaxf(fmaxf(a11[rg * 4], a11[rg * 4 + 1]),
                        fmaxf(a11[rg * 4 + 2], a11[rg * 4 + 3]));
      int p0 = 2 * rg + hi, p1 = 8 + 2 * rg + hi;
      erow[p0 * 64 + l31] = f2bf(fmaxf(m00 + b2_0, 0.f));
      erow[p0 * 64 + 32 + l31] = f2bf(fmaxf(m01 + b2_1, 0.f));
      erow[p1 * 64 + l31] = f2bf(fmaxf(m10 + b2_0, 0.f));
      erow[p1 * 64 + 32 + l31] = f2bf(fmaxf(m11 + b2_1, 0.f));
    }
  }
}

// ---------------------------------------------------------------------------
// Tail: deferred-normalization MIL pyramid with only TWO sync points.
// emb2u/emb3u carry unnormalized bag sums; 1/S folded into next level's
// accumulator (linear before tanh); final head divides by S1*S2*S3.
// ---------------------------------------------------------------------------
// 32 rows (row-major, stride 1024) -> wexp[0..31]=exp(sigmoid(score)), returns
// block sum of exp. 256 threads = 4 waves x 2 col-tiles (ATT=256).
__device__ float att_rows32(const ushortT* __restrict__ emb_rm,
                            const ushortT* __restrict__ Bp,
                            const float* __restrict__ bias,
                            const float* __restrict__ v, float vb0, float invS,
                            float* wexp, float (*part)[4], float* esc) {
  const int tid = threadIdx.x, wv = tid >> 6, lane = tid & 63;
  const int hi = lane >> 5, l31 = lane & 31;
  const ushortT* ap = emb_rm + (size_t)l31 * 1024 + hi * 8;
  const ushortT* bp0 = Bp + (size_t)(2 * wv) * 32768 + (size_t)lane * 8;
  const ushortT* bp1 = bp0 + 32768;

  f32x16 a0, a1;
#pragma unroll
  for (int z = 0; z < 16; ++z) { a0[z] = 0.f; a1[z] = 0.f; }

#pragma unroll 8
  for (int s = 0; s < 64; ++s) {
    bf16x8 af = *(const bf16x8*)(ap + s * 16);
    bf16x8 b0 = *(const bf16x8*)(bp0 + s * 512);
    bf16x8 b1 = *(const bf16x8*)(bp1 + s * 512);
    a0 = __builtin_amdgcn_mfma_f32_32x32x16_bf16(af, b0, a0, 0, 0, 0);
    a1 = __builtin_amdgcn_mfma_f32_32x32x16_bf16(af, b1, a1, 0, 0, 0);
  }

  const int c0 = wv * 64 + l31, c1 = c0 + 32;
  const float bc0 = bias[c0], vc0 = v[c0];
  const float bc1 = bias[c1], vc1 = v[c1];
#pragma unroll
  for (int r = 0; r < 16; ++r) {
    float p = tanhf(a0[r] * invS + bc0) * vc0 + tanhf(a1[r] * invS + bc1) * vc1;
#pragma unroll
    for (int off = 16; off >= 1; off >>= 1) p += __shfl_xor(p, off, 64);
    if (l31 == 0) part[(r & 3) + 8 * (r >> 2) + 4 * hi][wv] = p;
  }
  __syncthreads();
  if (tid < 32) {
    float ss = vb0 + part[tid][0] + part[tid][1] + part[tid][2] + part[tid][3];
    float e = expf(1.f / (1.f + expf(-ss)));
    wexp[tid] = e;
#pragma unroll
    for (int off = 16; off >= 1; off >>= 1) e += __shfl_xor(e, off, 64);
    if (tid == 0) esc[0] = e;
  }
  __syncthreads();
  return esc[0];
}

// emb_out rows {0,1} = unnormalized bag sums of the block's 32 rows.
__device__ void segsum_rm(const ushortT* __restrict__ emb_in,
                          const float* __restrict__ wexp,
                          ushortT* __restrict__ emb_out) {
  const int c4 = threadIdx.x * 4;
#pragma unroll
  for (int b = 0; b < 2; ++b) {
    f32x4 acc;
#pragma unroll
    for (int z = 0; z < 4; ++z) acc[z] = 0.f;
#pragma unroll
    for (int k = 0; k < 16; ++k) {
      u16x4 uu = *(const u16x4*)(emb_in + (size_t)(b * 16 + k) * 1024 + c4);
      float w = wexp[b * 16 + k];
      acc[0] += bf2f(uu[0]) * w;
      acc[1] += bf2f(uu[1]) * w;
      acc[2] += bf2f(uu[2]) * w;
      acc[3] += bf2f(uu[3]) * w;
    }
    u16x4 o;
#pragma unroll
    for (int z = 0; z < 4; ++z) o[z] = f2bf(acc[z]);
    *(u16x4*)(emb_out + (size_t)b * 1024 + c4) = o;
  }
}

__global__ __launch_bounds__(256, 2) void tail_kernel(
    const ushortT* __restrict__ emb1, const ushortT* __restrict__ BpA1,
    const ushortT* __restrict__ BpA2, const ushortT* __restrict__ BpA3,
    const float* __restrict__ a1b, const float* __restrict__ a1v,
    const float* __restrict__ a1vb, const float* __restrict__ a2b,
    const float* __restrict__ a2v, const float* __restrict__ a2vb,
    const float* __restrict__ a3b, const float* __restrict__ a3v,
    const float* __restrict__ a3vb, const float* __restrict__ u,
    ushortT* __restrict__ emb2u, ushortT* __restrict__ emb3u,
    unsigned* ctrl, float* __restrict__ out) {
  __shared__ float part[32][4];
  __shared__ float wexp[64];
  __shared__ float esc[1];
  __shared__ float Sv[2];
  __shared__ float redp[4];
  const int blk = blockIdx.x, tid = threadIdx.x;
  unsigned* ctr1 = ctrl;               // 8 lines, stride 32 uints (128B)
  float* fs1 = (float*)(ctrl + 256);   // 8 lines
  unsigned* ctr2 = ctrl + 512;         // 4 lines
  float* fs2 = (float*)(ctrl + 768);   // 4 lines

  // ---- level 1: att on own 32 rows + unnormalized segsum of own 2 bags ----
  float e1 = att_rows32(emb1 + (size_t)blk * 32768, BpA1, a1b, a1v, a1vb[0],
                        1.f, wexp, part, esc);
  segsum_rm(emb1 + (size_t)blk * 32768, wexp, emb2u + (size_t)blk * 2048);
  __syncthreads();
  if (tid == 0) {
    __threadfence();
    __hip_atomic_fetch_add(&fs1[(blk & 7) * 32], e1, __ATOMIC_RELAXED,
                           __HIP_MEMORY_SCOPE_AGENT);
    __hip_atomic_fetch_add(&ctr1[(blk & 7) * 32], 1u, __ATOMIC_RELEASE,
                           __HIP_MEMORY_SCOPE_AGENT);
  }
  if (blk >= 32) return;

  // ---- sync 1: wait for all 512 producers; gather S1 ----
  if (tid == 0) {
    unsigned t;
    do {
      t = 0;
      for (int i = 0; i < 8; ++i)
        t += __hip_atomic_load(&ctr1[i * 32], __ATOMIC_ACQUIRE,
                               __HIP_MEMORY_SCOPE_AGENT);
      if (t < 512) __builtin_amdgcn_s_sleep(2);
    } while (t < 512);
    __threadfence();
    float S = 0.f;
    for (int i = 0; i < 8; ++i)
      S += __hip_atomic_load(&fs1[i * 32], __ATOMIC_RELAXED,
                             __HIP_MEMORY_SCOPE_AGENT);
    Sv[0] = S;
  }
  __syncthreads();
  const float S1 = Sv[0];

  // ---- level 2 (32 blocks): scale 1/S1 folded into accumulator ----
  float e2 = att_rows32(emb2u + (size_t)blk * 32768, BpA2, a2b, a2v, a2vb[0],
                        1.f / S1, wexp, part, esc);
  segsum_rm(emb2u + (size_t)blk * 32768, wexp, emb3u + (size_t)blk * 2048);
  __syncthreads();
  if (tid == 0) {
    __threadfence();
    __hip_atomic_fetch_add(&fs2[(blk & 3) * 32], e2, __ATOMIC_RELAXED,
                           __HIP_MEMORY_SCOPE_AGENT);
    __hip_atomic_fetch_add(&ctr2[(blk & 3) * 32], 1u, __ATOMIC_RELEASE,
                           __HIP_MEMORY_SCOPE_AGENT);
  }
  if (blk >= 1) return;

  // ---- sync 2: wait for 32 producers; gather S2 ----
  if (tid == 0) {
    unsigned t;
    do {
      t = 0;
      for (int i = 0; i < 4; ++i)
        t += __hip_atomic_load(&ctr2[i * 32], __ATOMIC_ACQUIRE,
                               __HIP_MEMORY_SCOPE_AGENT);
      if (t < 32) __builtin_amdgcn_s_sleep(2);
    } while (t < 32);
    __threadfence();
    float S = 0.f;
    for (int i = 0; i < 4; ++i)
      S += __hip_atomic_load(&fs2[i * 32], __ATOMIC_RELAXED,
                             __HIP_MEMORY_SCOPE_AGENT);
    Sv[1] = S;
  }
  __syncthreads();
  const float S2 = Sv[1];
  const float inv12 = 1.f / (S1 * S2);

  // ---- level 3 (block 0): 64 rows in two att tiles ----
  float ea = att_rows32(emb3u, BpA3, a3b, a3v, a3vb[0], inv12, wexp, part, esc);
  __syncthreads();
  float eb = att_rows32(emb3u + 32768, BpA3, a3b, a3v, a3vb[0], inv12,
                        wexp + 32, part, esc);
  __syncthreads();
  const float S3 = ea + eb;

  // ---- head: z = (w3exp @ emb3u) . u / (S1*S2*S3) + cbdot ----
  const int c4 = tid * 4;
  f32x4 outer;
#pragma unroll
  for (int z = 0; z < 4; ++z) outer[z] = 0.f;
#pragma unroll
  for (int b = 0; b < 64; ++b) {
    float w = wexp[b];
    u16x4 uu = *(const u16x4*)(emb3u + (size_t)b * 1024 + c4);
    outer[0] += bf2f(uu[0]) * w;
    outer[1] += bf2f(uu[1]) * w;
    outer[2] += bf2f(uu[2]) * w;
    outer[3] += bf2f(uu[3]) * w;
  }
  float zp = outer[0] * u[c4] + outer[1] * u[c4 + 1] + outer[2] * u[c4 + 2] +
             outer[3] * u[c4 + 3];
#pragma unroll
  for (int off = 32; off; off >>= 1) zp += __shfl_xor(zp, off, 64);
  if ((tid & 63) == 0) redp[tid >> 6] = zp;
  __syncthreads();
  if (tid == 0) {
    float z = (redp[0] + redp[1] + redp[2] + redp[3]) / (S1 * S2 * S3) +
              u[1024];
    out[0] = 1.f / (1.f + expf(-z));
  }
}

// ---------------------------------------------------------------------------
extern "C" void kernel_launch(void* const* d_in, const int* in_sizes, int n_in,
                              void* d_out, int out_size, void* d_ws,
                              size_t ws_size, hipStream_t stream) {
  const float* x       = (const float*)d_in[0];
  const float* conv1_w = (const float*)d_in[1];
  const float* conv1_b = (const float*)d_in[2];
  const float* conv2_w = (const float*)d_in[3];
  const float* conv2_b = (const float*)d_in[4];
  const float* att1_W  = (const float*)d_in[5];
  const float* att1_b  = (const float*)d_in[6];
  const float* att1_v  = (const float*)d_in[7];
  const float* att1_vb = (const float*)d_in[8];
  const float* att2_W  = (const float*)d_in[9];
  const float* att2_b  = (const float*)d_in[10];
  const float* att2_v  = (const float*)d_in[11];
  const float* att2_vb = (const float*)d_in[12];
  const float* att3_W  = (const float*)d_in[13];
  const float* att3_b  = (const float*)d_in[14];
  const float* att3_v  = (const float*)d_in[15];
  const float* att3_vb = (const float*)d_in[16];
  const float* cls_W   = (const float*)d_in[17];
  const float* cls_b   = (const float*)d_in[18];
  const float* out_W   = (const float*)d_in[19];
  const float* out_b   = (const float*)d_in[20];

  char* p = (char*)d_ws;
  unsigned* ctrl = (unsigned*)p; p += 4096;           // sync lines (memset 0)
  ushortT* emb1  = (ushortT*)p;  p += (size_t)16384 * 1024 * 2;
  ushortT* Bp1   = (ushortT*)p;  p += 2048;
  ushortT* Bp2   = (ushortT*)p;  p += 102400;
  ushortT* BpA1  = (ushortT*)p;  p += 524288;
  ushortT* BpA2  = (ushortT*)p;  p += 524288;
  ushortT* BpA3  = (ushortT*)p;  p += 524288;
  float* u       = (float*)p;    p += 8192;           // u[0..1023] + cbdot
  ushortT* emb2u = (ushortT*)p;  p += (size_t)1024 * 1024 * 2;
  ushortT* emb3u = (ushortT*)p;  p += 64 * 1024 * 2;

  prepack_kernel<<<3533, 256, 0, stream>>>(conv1_w, conv2_w, att1_W, att2_W,
                                           att3_W, cls_W, cls_b, out_W, out_b,
                                           Bp1, Bp2, BpA1, BpA2, BpA3, u);
  fused_conv_mfma_kernel<<<4096, 256, 0, stream>>>(x, Bp1, conv1_b, Bp2,
                                                   conv2_b, emb1);
  hipMemsetAsync(ctrl, 0, 4096, stream);
  tail_kernel<<<512, 256, 0, stream>>>(
      emb1, BpA1, BpA2, BpA3, att1_b, att1_v, att1_vb, att2_b, att2_v, att2_vb,
      att3_b, att3_v, att3_vb, u, emb2u, emb3u, ctrl, (float*)d_out);
}

// Round 9
// 393.167 us; speedup vs baseline: 2.9930x; 1.1525x over previous
//
#include <hip/hip_runtime.h>
#include <hip/hip_bf16.h>
#include <math.h>

typedef float f32x4 __attribute__((ext_vector_type(4)));
using bf16x8 = __attribute__((ext_vector_type(8))) short;
using f32x16 = __attribute__((ext_vector_type(16))) float;
typedef unsigned short ushortT;
using u16x4 = __attribute__((ext_vector_type(4))) unsigned short;

__device__ __forceinline__ ushortT f2bf(float f) {
  unsigned int u = __builtin_bit_cast(unsigned int, f);
  u = (u + 0x7FFFu + ((u >> 16) & 1u)) >> 16;
  return (ushortT)u;
}
__device__ __forceinline__ float bf2f(ushortT u) {
  return __builtin_bit_cast(float, (unsigned int)u << 16);
}
__device__ __forceinline__ void gload_lds16(const void* gsrc, void* ldst) {
  __builtin_amdgcn_global_load_lds(
      (const __attribute__((address_space(1))) unsigned int*)gsrc,
      (__attribute__((address_space(3))) unsigned int*)ldst, 16, 0, 0);
}

// ---------------------------------------------------------------------------
// Prepack: bf16 MFMA fragment layouts + u = cls_W @ out_W + cbdot at u[1024].
// ---------------------------------------------------------------------------
__global__ __launch_bounds__(256) void prepack_kernel(
    const float* __restrict__ w1, const float* __restrict__ w2,
    const float* __restrict__ aW1, const float* __restrict__ aW2,
    const float* __restrict__ aW3, const float* __restrict__ cls_W,
    const float* __restrict__ cls_b, const float* __restrict__ out_W,
    const float* __restrict__ out_b, ushortT* __restrict__ Bp1,
    ushortT* __restrict__ Bp2, ushortT* __restrict__ BpA1,
    ushortT* __restrict__ BpA2, ushortT* __restrict__ BpA3,
    float* __restrict__ u) {
  const int i = blockIdx.x * 256 + threadIdx.x;
  const int n1 = 1024, n2 = 51200, nA = 262144, nU = 65536;
  if (i < n1) {
    int nt = i >> 9, l = (i >> 3) & 63, j = i & 7;
    int tap = ((l >> 4) << 3) + j, ch = nt * 16 + (l & 15);
    Bp1[i] = (tap < 25) ? f2bf(w1[tap * 32 + ch]) : (ushortT)0;
  } else if (i < n1 + n2) {
    int t = i - n1;
    int co = t & 63, k = t >> 6;  // coalesced read over co
    int s = k >> 4, hi = (k >> 3) & 1, j = k & 7;
    int nt = co >> 5, l31 = co & 31;
    Bp2[(s * 2 + nt) * 512 + (hi * 32 + l31) * 8 + j] = f2bf(w2[k * 64 + co]);
  } else if (i < n1 + n2 + 3 * nA) {
    int t = i - n1 - n2;
    int m = t >> 18, r = t & (nA - 1);
    const float* aW = (m == 0) ? aW1 : ((m == 1) ? aW2 : aW3);
    ushortT* dst = (m == 0) ? BpA1 : ((m == 1) ? BpA2 : BpA3);
    int col = r & 255, k = r >> 8;  // coalesced read over col
    int nt = col >> 5, l31 = col & 31;
    int s = k >> 4, hi = (k >> 3) & 1, j = k & 7;
    dst[nt * 32768 + s * 512 + (hi * 32 + l31) * 8 + j] =
        f2bf(aW[k * 256 + col]);
  } else if (i < n1 + n2 + 3 * nA + nU) {
    int t = i - (n1 + n2 + 3 * nA);
    int k = t >> 6, lane = t & 63;
    float p = 0.f;
#pragma unroll
    for (int j = 0; j < 8; ++j) {
      int jj = lane + j * 64;
      p += cls_W[k * 512 + jj] * out_W[jj];
    }
#pragma unroll
    for (int off = 32; off; off >>= 1) p += __shfl_xor(p, off, 64);
    if (lane == 0) u[k] = p;
  } else if (i < n1 + n2 + 3 * nA + nU + 64) {
    int lane = i - (n1 + n2 + 3 * nA + nU);
    float p = 0.f;
#pragma unroll
    for (int j = 0; j < 8; ++j) {
      int jj = lane * 8 + j;
      p += cls_b[jj] * out_W[jj];
    }
#pragma unroll
    for (int off = 32; off; off >>= 1) p += __shfl_xor(p, off, 64);
    if (lane == 0) u[1024] = p + out_b[0];
  }
}

// ---------------------------------------------------------------------------
// Fused conv — VERBATIM round-3 config (measured ~187us).
// ---------------------------------------------------------------------------
#define PADW 40
__global__ __launch_bounds__(256, 2) void fused_conv_mfma_kernel(
    const float* __restrict__ x, const ushortT* __restrict__ Bp1,
    const float* __restrict__ b1g, const ushortT* __restrict__ Bp2,
    const float* __restrict__ b2g, ushortT* __restrict__ emb1) {
  __shared__ ushortT xs[4][784];
  __shared__ ushortT h1s[4][144 * PADW];
  __shared__ ushortT Bbuf[2][4096];  // 8KB chunks = 4 K-steps

  const int tid = threadIdx.x, wv = tid >> 6, lane = tid & 63;
  const int inst = blockIdx.x * 4 + wv;

  {
    int base = wv * 2048;
    gload_lds16((const char*)Bp2 + base + lane * 16, (char*)&Bbuf[0][0] + base);
    gload_lds16((const char*)Bp2 + base + 1024 + lane * 16,
                (char*)&Bbuf[0][0] + base + 1024);
  }

  const float* xg = x + (size_t)inst * 784;
  for (int i = lane; i < 784; i += 64) xs[wv][i] = f2bf(xg[i]);
  __syncthreads();

  // ---------------- conv1 via MFMA (wave owns instance) ----------------
  {
    const int arow = lane & 15, kg = lane >> 4;
    int koff[8], kval[8];
#pragma unroll
    for (int j = 0; j < 8; ++j) {
      int tap = kg * 8 + j;
      int ky = (tap * 13) >> 6;
      int kx = tap - ky * 5;
      kval[j] = (tap < 25);
      koff[j] = kval[j] ? (ky * 28 + kx) : 0;
    }
    bf16x8 w1f0 = *(const bf16x8*)&Bp1[lane * 8];
    bf16x8 w1f1 = *(const bf16x8*)&Bp1[(64 + lane) * 8];
    const float bA = b1g[arow], bB = b1g[16 + arow];

#pragma unroll 4
    for (int g = 0; g < 36; ++g) {
      int R = g * 16 + arow;
      int q = R >> 2, quad = R & 3;
      int qy = q / 12, qx = q - qy * 12;
      int base = (2 * qy + (quad >> 1)) * 28 + 2 * qx + (quad & 1);
      bf16x8 a;
#pragma unroll
      for (int j = 0; j < 8; ++j) {
        ushortT vv = xs[wv][base + koff[j]];
        a[j] = (short)(kval[j] ? vv : (ushortT)0);
      }
      f32x4 c0, c1;
#pragma unroll
      for (int z = 0; z < 4; ++z) { c0[z] = 0.f; c1[z] = 0.f; }
      c0 = __builtin_amdgcn_mfma_f32_16x16x32_bf16(a, w1f0, c0, 0, 0, 0);
      c1 = __builtin_amdgcn_mfma_f32_16x16x32_bf16(a, w1f1, c1, 0, 0, 0);
      int qo = g * 4 + kg;
      float m0 = fmaxf(fmaxf(c0[0], c0[1]), fmaxf(c0[2], c0[3]));
      float m1 = fmaxf(fmaxf(c1[0], c1[1]), fmaxf(c1[2], c1[3]));
      h1s[wv][qo * PADW + arow] = f2bf(fmaxf(m0 + bA, 0.f));
      h1s[wv][qo * PADW + 16 + arow] = f2bf(fmaxf(m1 + bB, 0.f));
    }
  }
  __syncthreads();

  // ---------------- conv2 via MFMA (wave owns instance, 64x64) -----------
  {
    const int hi = lane >> 5, l31 = lane & 31;
    int rowbase0, rowbase1;
    {
      int q2 = l31 >> 2, quad2 = l31 & 3;
      rowbase0 = (2 * (q2 >> 2) + (quad2 >> 1)) * 12 + 2 * (q2 & 3) + (quad2 & 1);
      q2 = (32 + l31) >> 2;
      rowbase1 = (2 * (q2 >> 2) + (quad2 >> 1)) * 12 + 2 * (q2 & 3) + (quad2 & 1);
    }
    const ushortT* h1w = &h1s[wv][0];

    f32x16 a00, a01, a10, a11;
#pragma unroll
    for (int z = 0; z < 16; ++z) { a00[z] = 0.f; a01[z] = 0.f; a10[z] = 0.f; a11[z] = 0.f; }

    for (int c = 0; c < 13; ++c) {
      if (c < 12) {
        char* dstb = (char*)&Bbuf[(c + 1) & 1][0];
        const char* srcb = (const char*)Bp2 + (size_t)(c + 1) * 8192;
        if (c + 1 < 12) {
          gload_lds16(srcb + wv * 2048 + lane * 16, dstb + wv * 2048);
          gload_lds16(srcb + wv * 2048 + 1024 + lane * 16,
                      dstb + wv * 2048 + 1024);
        } else {
          gload_lds16(srcb + wv * 1024 + lane * 16, dstb + wv * 1024);
        }
      }
      const ushortT* bb = &Bbuf[c & 1][0];
      const int ns = (c < 12) ? 4 : 2;
#pragma unroll
      for (int i = 0; i < 4; ++i) {
        if (i < ns) {
          int s = c * 4 + i;
          int tap = s >> 1;
          int ky = (tap * 13) >> 6, kx = tap - ky * 5;
          int aoff = (ky * 12 + kx) * PADW + ((s & 1) << 4) + hi * 8;
          bf16x8 bf0 = *(const bf16x8*)&bb[i * 1024 + lane * 8];
          bf16x8 bf1 = *(const bf16x8*)&bb[i * 1024 + 512 + lane * 8];
          bf16x8 af0 = *(const bf16x8*)&h1w[rowbase0 * PADW + aoff];
          bf16x8 af1 = *(const bf16x8*)&h1w[rowbase1 * PADW + aoff];
          a00 = __builtin_amdgcn_mfma_f32_32x32x16_bf16(af0, bf0, a00, 0, 0, 0);
          a01 = __builtin_amdgcn_mfma_f32_32x32x16_bf16(af0, bf1, a01, 0, 0, 0);
          a10 = __builtin_amdgcn_mfma_f32_32x32x16_bf16(af1, bf0, a10, 0, 0, 0);
          a11 = __builtin_amdgcn_mfma_f32_32x32x16_bf16(af1, bf1, a11, 0, 0, 0);
        }
      }
      __syncthreads();
    }

    const float b2_0 = b2g[l31], b2_1 = b2g[32 + l31];
    ushortT* erow = emb1 + (size_t)inst * 1024;
#pragma unroll
    for (int rg = 0; rg < 4; ++rg) {
      float m00 = fmaxf(fmaxf(a00[rg * 4], a00[rg * 4 + 1]),
                        fmaxf(a00[rg * 4 + 2], a00[rg * 4 + 3]));
      float m01 = fmaxf(fmaxf(a01[rg * 4], a01[rg * 4 + 1]),
                        fmaxf(a01[rg * 4 + 2], a01[rg * 4 + 3]));
      float m10 = fmaxf(fmaxf(a10[rg * 4], a10[rg * 4 + 1]),
                        fmaxf(a10[rg * 4 + 2], a10[rg * 4 + 3]));
      float m11 = fmaxf(fmaxf(a11[rg * 4], a11[rg * 4 + 1]),
                        fmaxf(a11[rg * 4 + 2], a11[rg * 4 + 3]));
      int p0 = 2 * rg + hi, p1 = 8 + 2 * rg + hi;
      erow[p0 * 64 + l31] = f2bf(fmaxf(m00 + b2_0, 0.f));
      erow[p0 * 64 + 32 + l31] = f2bf(fmaxf(m01 + b2_1, 0.f));
      erow[p1 * 64 + l31] = f2bf(fmaxf(m10 + b2_0, 0.f));
      erow[p1 * 64 + 32 + l31] = f2bf(fmaxf(m11 + b2_1, 0.f));
    }
  }
}

// ---------------------------------------------------------------------------
// Tail, deferred normalization, split into 3 kernels (no fences, no spins —
// kernel boundaries provide device-wide coherence).
// ---------------------------------------------------------------------------
__device__ float att_rows32(const ushortT* __restrict__ emb_rm,
                            const ushortT* __restrict__ Bp,
                            const float* __restrict__ bias,
                            const float* __restrict__ v, float vb0, float invS,
                            float* wexp, float (*part)[4], float* esc) {
  const int tid = threadIdx.x, wv = tid >> 6, lane = tid & 63;
  const int hi = lane >> 5, l31 = lane & 31;
  const ushortT* ap = emb_rm + (size_t)l31 * 1024 + hi * 8;
  const ushortT* bp0 = Bp + (size_t)(2 * wv) * 32768 + (size_t)lane * 8;
  const ushortT* bp1 = bp0 + 32768;

  f32x16 a0, a1;
#pragma unroll
  for (int z = 0; z < 16; ++z) { a0[z] = 0.f; a1[z] = 0.f; }

#pragma unroll 8
  for (int s = 0; s < 64; ++s) {
    bf16x8 af = *(const bf16x8*)(ap + s * 16);
    bf16x8 b0 = *(const bf16x8*)(bp0 + s * 512);
    bf16x8 b1 = *(const bf16x8*)(bp1 + s * 512);
    a0 = __builtin_amdgcn_mfma_f32_32x32x16_bf16(af, b0, a0, 0, 0, 0);
    a1 = __builtin_amdgcn_mfma_f32_32x32x16_bf16(af, b1, a1, 0, 0, 0);
  }

  const int c0 = wv * 64 + l31, c1 = c0 + 32;
  const float bc0 = bias[c0], vc0 = v[c0];
  const float bc1 = bias[c1], vc1 = v[c1];
#pragma unroll
  for (int r = 0; r < 16; ++r) {
    float p = tanhf(a0[r] * invS + bc0) * vc0 + tanhf(a1[r] * invS + bc1) * vc1;
#pragma unroll
    for (int off = 16; off >= 1; off >>= 1) p += __shfl_xor(p, off, 64);
    if (l31 == 0) part[(r & 3) + 8 * (r >> 2) + 4 * hi][wv] = p;
  }
  __syncthreads();
  if (tid < 32) {
    float ss = vb0 + part[tid][0] + part[tid][1] + part[tid][2] + part[tid][3];
    float e = expf(1.f / (1.f + expf(-ss)));
    wexp[tid] = e;
#pragma unroll
    for (int off = 16; off >= 1; off >>= 1) e += __shfl_xor(e, off, 64);
    if (tid == 0) esc[0] = e;
  }
  __syncthreads();
  return esc[0];
}

__device__ void segsum_rm(const ushortT* __restrict__ emb_in,
                          const float* __restrict__ wexp,
                          ushortT* __restrict__ emb_out) {
  const int c4 = threadIdx.x * 4;
#pragma unroll
  for (int b = 0; b < 2; ++b) {
    f32x4 acc;
#pragma unroll
    for (int z = 0; z < 4; ++z) acc[z] = 0.f;
#pragma unroll
    for (int k = 0; k < 16; ++k) {
      u16x4 uu = *(const u16x4*)(emb_in + (size_t)(b * 16 + k) * 1024 + c4);
      float w = wexp[b * 16 + k];
      acc[0] += bf2f(uu[0]) * w;
      acc[1] += bf2f(uu[1]) * w;
      acc[2] += bf2f(uu[2]) * w;
      acc[3] += bf2f(uu[3]) * w;
    }
    u16x4 o;
#pragma unroll
    for (int z = 0; z < 4; ++z) o[z] = f2bf(acc[z]);
    *(u16x4*)(emb_out + (size_t)b * 1024 + c4) = o;
  }
}

// tailA: 512 blocks — att1 on own 32 rows + unnormalized segsum + S1 atomic.
__global__ __launch_bounds__(256, 2) void tailA_kernel(
    const ushortT* __restrict__ emb1, const ushortT* __restrict__ BpA1,
    const float* __restrict__ a1b, const float* __restrict__ a1v,
    const float* __restrict__ a1vb, ushortT* __restrict__ emb2u,
    float* __restrict__ fs) {
  __shared__ float part[32][4];
  __shared__ float wexp[32];
  __shared__ float esc[1];
  const int blk = blockIdx.x;
  float e1 = att_rows32(emb1 + (size_t)blk * 32768, BpA1, a1b, a1v, a1vb[0],
                        1.f, wexp, part, esc);
  segsum_rm(emb1 + (size_t)blk * 32768, wexp, emb2u + (size_t)blk * 2048);
  if (threadIdx.x == 0) atomicAdd(&fs[0], e1);
}

// tailB: 32 blocks — att2 (1/S1 folded) + unnormalized segsum + S2 atomic.
__global__ __launch_bounds__(256, 2) void tailB_kernel(
    const ushortT* __restrict__ emb2u, const ushortT* __restrict__ BpA2,
    const float* __restrict__ a2b, const float* __restrict__ a2v,
    const float* __restrict__ a2vb, const float* __restrict__ fs_in,
    ushortT* __restrict__ emb3u, float* __restrict__ fs) {
  __shared__ float part[32][4];
  __shared__ float wexp[32];
  __shared__ float esc[1];
  const int blk = blockIdx.x;
  float invS1 = 1.f / fs_in[0];
  float e2 = att_rows32(emb2u + (size_t)blk * 32768, BpA2, a2b, a2v, a2vb[0],
                        invS1, wexp, part, esc);
  segsum_rm(emb2u + (size_t)blk * 32768, wexp, emb3u + (size_t)blk * 2048);
  if (threadIdx.x == 0) atomicAdd(&fs[1], e2);
}

// tailC: 1 block — att3 (two 32-row tiles) + head.
__global__ __launch_bounds__(256) void tailC_kernel(
    const ushortT* __restrict__ emb3u, const ushortT* __restrict__ BpA3,
    const float* __restrict__ a3b, const float* __restrict__ a3v,
    const float* __restrict__ a3vb, const float* __restrict__ fs,
    const float* __restrict__ u, float* __restrict__ out) {
  __shared__ float part[32][4];
  __shared__ float wexp[64];
  __shared__ float esc[1];
  __shared__ float redp[4];
  const int tid = threadIdx.x;
  const float S1 = fs[0], S2 = fs[1];
  const float inv12 = 1.f / (S1 * S2);

  float ea = att_rows32(emb3u, BpA3, a3b, a3v, a3vb[0], inv12, wexp, part, esc);
  __syncthreads();
  float eb = att_rows32(emb3u + 32768, BpA3, a3b, a3v, a3vb[0], inv12,
                        wexp + 32, part, esc);
  __syncthreads();
  const float S3 = ea + eb;

  const int c4 = tid * 4;
  f32x4 outer;
#pragma unroll
  for (int z = 0; z < 4; ++z) outer[z] = 0.f;
#pragma unroll
  for (int b = 0; b < 64; ++b) {
    float w = wexp[b];
    u16x4 uu = *(const u16x4*)(emb3u + (size_t)b * 1024 + c4);
    outer[0] += bf2f(uu[0]) * w;
    outer[1] += bf2f(uu[1]) * w;
    outer[2] += bf2f(uu[2]) * w;
    outer[3] += bf2f(uu[3]) * w;
  }
  float zp = outer[0] * u[c4] + outer[1] * u[c4 + 1] + outer[2] * u[c4 + 2] +
             outer[3] * u[c4 + 3];
#pragma unroll
  for (int off = 32; off; off >>= 1) zp += __shfl_xor(zp, off, 64);
  if ((tid & 63) == 0) redp[tid >> 6] = zp;
  __syncthreads();
  if (tid == 0) {
    float z = (redp[0] + redp[1] + redp[2] + redp[3]) / (S1 * S2 * S3) +
              u[1024];
    out[0] = 1.f / (1.f + expf(-z));
  }
}

// ---------------------------------------------------------------------------
extern "C" void kernel_launch(void* const* d_in, const int* in_sizes, int n_in,
                              void* d_out, int out_size, void* d_ws,
                              size_t ws_size, hipStream_t stream) {
  const float* x       = (const float*)d_in[0];
  const float* conv1_w = (const float*)d_in[1];
  const float* conv1_b = (const float*)d_in[2];
  const float* conv2_w = (const float*)d_in[3];
  const float* conv2_b = (const float*)d_in[4];
  const float* att1_W  = (const float*)d_in[5];
  const float* att1_b  = (const float*)d_in[6];
  const float* att1_v  = (const float*)d_in[7];
  const float* att1_vb = (const float*)d_in[8];
  const float* att2_W  = (const float*)d_in[9];
  const float* att2_b  = (const float*)d_in[10];
  const float* att2_v  = (const float*)d_in[11];
  const float* att2_vb = (const float*)d_in[12];
  const float* att3_W  = (const float*)d_in[13];
  const float* att3_b  = (const float*)d_in[14];
  const float* att3_v  = (const float*)d_in[15];
  const float* att3_vb = (const float*)d_in[16];
  const float* cls_W   = (const float*)d_in[17];
  const float* cls_b   = (const float*)d_in[18];
  const float* out_W   = (const float*)d_in[19];
  const float* out_b   = (const float*)d_in[20];

  char* p = (char*)d_ws;
  float* fs      = (float*)p;    p += 256;            // fs[0]=S1, fs[1]=S2
  ushortT* emb1  = (ushortT*)p;  p += (size_t)16384 * 1024 * 2;
  ushortT* Bp1   = (ushortT*)p;  p += 2048;
  ushortT* Bp2   = (ushortT*)p;  p += 102400;
  ushortT* BpA1  = (ushortT*)p;  p += 524288;
  ushortT* BpA2  = (ushortT*)p;  p += 524288;
  ushortT* BpA3  = (ushortT*)p;  p += 524288;
  float* u       = (float*)p;    p += 8192;           // u[0..1023] + cbdot
  ushortT* emb2u = (ushortT*)p;  p += (size_t)1024 * 1024 * 2;
  ushortT* emb3u = (ushortT*)p;  p += 64 * 1024 * 2;

  prepack_kernel<<<3533, 256, 0, stream>>>(conv1_w, conv2_w, att1_W, att2_W,
                                           att3_W, cls_W, cls_b, out_W, out_b,
                                           Bp1, Bp2, BpA1, BpA2, BpA3, u);
  hipMemsetAsync(fs, 0, 256, stream);
  fused_conv_mfma_kernel<<<4096, 256, 0, stream>>>(x, Bp1, conv1_b, Bp2,
                                                   conv2_b, emb1);
  tailA_kernel<<<512, 256, 0, stream>>>(emb1, BpA1, att1_b, att1_v, att1_vb,
                                        emb2u, fs);
  tailB_kernel<<<32, 256, 0, stream>>>(emb2u, BpA2, att2_b, att2_v, att2_vb,
                                       fs, emb3u, fs);
  tailC_kernel<<<1, 256, 0, stream>>>(emb3u, BpA3, att3_b, att3_v, att3_vb,
                                      fs, u, (float*)d_out);
}